// Round 1
// baseline (1634.898 us; speedup 1.0000x reference)
//
#include <hip/hip_runtime.h>
#include <math.h>

// Problem constants (b=2, n=4096, k=32, d0=64, d1=16, L=2, rh=16, HEADS=4)
#define BB    2
#define NN    4096
#define KK    32
#define D0    64
#define D1    16
#define D13   48      // d1*3
#define RHD   16
#define NHEAD 4
#define NLAYER 2
#define EPS   1e-6f
#define SCALE 0.18898223650461363f   // 1/sqrt(16 + 12)

__device__ __forceinline__ float wred(float v) {
    #pragma unroll
    for (int o = 32; o > 0; o >>= 1) v += __shfl_xor(v, o, 64);
    return v;
}

__device__ __forceinline__ float gelu_t(float x) {
    // jax.nn.gelu default (approximate=True, tanh form)
    float x3 = x * x * x;
    return 0.5f * x * (1.0f + tanhf(0.7978845608028654f * (x + 0.044715f * x3)));
}

// ---------------- geometry: rel, dist, rhat ----------------
__global__ void geom_kernel(const float* __restrict__ coords,
                            const int* __restrict__ nbr,
                            float* __restrict__ rhat,
                            float* __restrict__ dist) {
    int e = blockIdx.x * blockDim.x + threadIdx.x;
    if (e >= BB * NN * KK) return;
    int bn = e / KK;          // b*NN + i
    int bb = bn / NN;
    int j  = nbr[e];
    const float* cs = coords + (size_t)bn * 3;
    const float* cn = coords + ((size_t)bb * NN + j) * 3;
    float rx = cn[0] - cs[0], ry = cn[1] - cs[1], rz = cn[2] - cs[2];
    float d  = sqrtf(rx * rx + ry * ry + rz * rz);
    float iv = 1.0f / (d + EPS);
    rhat[e * 3 + 0] = rx * iv;
    rhat[e * 3 + 1] = ry * iv;
    rhat[e * 3 + 2] = rz * iv;
    dist[e] = d;
}

// ---------------- prenorm: g0 = LN(f0), g1 = RMS(f1) ----------------
__global__ __launch_bounds__(64) void prenorm_kernel(const float* __restrict__ f0,
                                                     const float* __restrict__ f1,
                                                     float* __restrict__ g0,
                                                     float* __restrict__ g1) {
    int node = blockIdx.x;
    int lane = threadIdx.x;
    float x  = f0[(size_t)node * D0 + lane];
    float mu = wred(x) * (1.0f / D0);
    float dv = x - mu;
    float var = wred(dv * dv) * (1.0f / D0);
    g0[(size_t)node * D0 + lane] = dv * rsqrtf(var + EPS);

    float w = (lane < D13) ? f1[(size_t)node * D13 + lane] : 0.0f;
    float t = wred(w * w);
    float rms = rsqrtf(t * (1.0f / D1) + EPS);
    if (lane < D13) g1[(size_t)node * D13 + lane] = w * rms;
}

// ---------------- fused attention (one block per node) ----------------
__global__ __launch_bounds__(256) void attn_kernel(
    const float* __restrict__ g0g, const float* __restrict__ g1g,
    const int* __restrict__ nbr_idx,
    const float* __restrict__ rhatg, const float* __restrict__ distg,
    const float* __restrict__ Wq0, const float* __restrict__ Wq1,
    const float* __restrict__ Wk00, const float* __restrict__ Wk10,
    const float* __restrict__ Wk01, const float* __restrict__ Wk11,
    const float* __restrict__ Wk11r,
    const float* __restrict__ Wv00, const float* __restrict__ Wv10,
    const float* __restrict__ Wv01, const float* __restrict__ Wv11,
    const float* __restrict__ Wv11r,
    const float* __restrict__ Rw1, const float* __restrict__ Rb1,
    const float* __restrict__ Rw20, const float* __restrict__ Rw21,
    const float* __restrict__ Wo0, const float* __restrict__ Wo1,
    float* __restrict__ f0b, float* __restrict__ f1b) {

    int node = blockIdx.x;
    int bb   = node / NN;
    int tid  = threadIdx.x;

    __shared__ float g0s[D0], g1s[D13], q0s[D0], q1s[D13];
    __shared__ int   nbrs[KK];
    __shared__ float dsts[KK], rhts[KK * 3];
    __shared__ float h0s[KK][D0];     // gathered neighbor g0
    __shared__ float h1s[KK][D13];    // gathered neighbor g1
    __shared__ float d1s[KK][D1];     // dot1
    __shared__ float rhfs[KK][RHD];   // radial hidden
    __shared__ float k0s[KK][D0], v0s[KK][D0];
    __shared__ float k1s[KK][D13], v1s[KK][D13];
    __shared__ float lgs[KK][NHEAD];
    __shared__ float o0s[D0], o1s[D13];

    // ---- P0: load own-node data + neighbor meta ----
    if (tid < 64)       g0s[tid] = g0g[(size_t)node * D0 + tid];
    else if (tid < 112) g1s[tid - 64] = g1g[(size_t)node * D13 + (tid - 64)];
    else if (tid < 144) nbrs[tid - 112] = nbr_idx[(size_t)node * KK + (tid - 112)];
    else if (tid < 176) dsts[tid - 144] = distg[(size_t)node * KK + (tid - 144)];
    if (tid < 96) rhts[tid] = rhatg[(size_t)node * 96 + tid];
    __syncthreads();

    // ---- P1: q projections + neighbor gather ----
    if (tid < 64) {
        float acc = 0.0f;
        #pragma unroll
        for (int c = 0; c < D0; c++) acc += g0s[c] * Wq0[c * D0 + tid];
        q0s[tid] = acc;
    } else if (tid < 112) {
        int idx = tid - 64, e = idx / 3, m = idx % 3;
        float acc = 0.0f;
        #pragma unroll
        for (int c = 0; c < D1; c++) acc += g1s[c * 3 + m] * Wq1[c * D1 + e];
        q1s[idx] = acc;
    }
    for (int t = tid; t < KK * (D0 + D13); t += 256) {
        if (t < KK * D0) {
            int j = t >> 6, c = t & 63;
            h0s[j][c] = g0g[((size_t)bb * NN + nbrs[j]) * D0 + c];
        } else {
            int t2 = t - KK * D0;
            int j = t2 / D13, c = t2 % D13;
            h1s[j][c] = g1g[((size_t)bb * NN + nbrs[j]) * D13 + c];
        }
    }
    __syncthreads();

    // ---- P2a: dot1 and radial hidden ----
    for (int t = tid; t < 2 * KK * D1; t += 256) {
        if (t < KK * D1) {
            int j = t >> 4, c = t & 15;
            d1s[j][c] = h1s[j][c * 3 + 0] * rhts[j * 3 + 0]
                      + h1s[j][c * 3 + 1] * rhts[j * 3 + 1]
                      + h1s[j][c * 3 + 2] * rhts[j * 3 + 2];
        } else {
            int t2 = t - KK * D1;
            int j = t2 >> 4, u = t2 & 15;
            rhfs[j][u] = gelu_t(dsts[j] * Rw1[u] + Rb1[u]);
        }
    }
    __syncthreads();

    // ---- P2b: k0, v0 per (neighbor, d0-channel) ----
    for (int t = tid; t < KK * D0; t += 256) {
        int j = t >> 6, e = t & 63;
        float r0 = 0.0f;
        #pragma unroll
        for (int u = 0; u < RHD; u++) r0 += rhfs[j][u] * Rw20[u * D0 + e];
        float ak = 0.0f, av = 0.0f;
        #pragma unroll
        for (int c = 0; c < D0; c++) {
            float h = h0s[j][c];
            ak += h * Wk00[c * D0 + e];
            av += h * Wv00[c * D0 + e];
        }
        #pragma unroll
        for (int c = 0; c < D1; c++) {
            float dd = d1s[j][c];
            ak += dd * Wk10[c * D0 + e];
            av += dd * Wv10[c * D0 + e];
        }
        k0s[j][e] = ak * r0;
        v0s[j][e] = av * r0;
    }
    // ---- P2c: k1, v1 per (neighbor, d1-channel) ----
    for (int t = tid; t < KK * D1; t += 256) {
        int j = t >> 4, e = t & 15;
        float r1 = 0.0f;
        #pragma unroll
        for (int u = 0; u < RHD; u++) r1 += rhfs[j][u] * Rw21[u * D1 + e];
        float a01k = 0.0f, a01v = 0.0f;
        #pragma unroll
        for (int c = 0; c < D0; c++) {
            float h = h0s[j][c];
            a01k += h * Wk01[c * D1 + e];
            a01v += h * Wv01[c * D1 + e];
        }
        float a11k = 0.0f, a11v = 0.0f;
        #pragma unroll
        for (int c = 0; c < D1; c++) {
            float dd = d1s[j][c];
            a11k += dd * Wk11r[c * D1 + e];
            a11v += dd * Wv11r[c * D1 + e];
        }
        float sk = a01k + a11k, sv = a01v + a11v;
        #pragma unroll
        for (int m = 0; m < 3; m++) {
            float hk = 0.0f, hv = 0.0f;
            #pragma unroll
            for (int c = 0; c < D1; c++) {
                float h1v = h1s[j][c * 3 + m];
                hk += h1v * Wk11[c * D1 + e];
                hv += h1v * Wv11[c * D1 + e];
            }
            float rh_m = rhts[j * 3 + m];
            k1s[j][e * 3 + m] = (sk * rh_m + hk) * r1;
            v1s[j][e * 3 + m] = (sv * rh_m + hv) * r1;
        }
    }
    __syncthreads();

    // ---- P2d: logits ----
    if (tid < KK * NHEAD) {
        int j = tid >> 2, h = tid & 3;
        float acc = 0.0f;
        #pragma unroll
        for (int c = 0; c < 16; c++) acc += q0s[h * 16 + c] * k0s[j][h * 16 + c];
        #pragma unroll
        for (int cc = 0; cc < 4; cc++) {
            int e = h * 4 + cc;
            #pragma unroll
            for (int m = 0; m < 3; m++) acc += q1s[e * 3 + m] * k1s[j][e * 3 + m];
        }
        lgs[j][h] = acc * SCALE;
    }
    __syncthreads();

    // ---- P3: softmax over neighbors per head ----
    if (tid < NHEAD) {
        int h = tid;
        float mx = -1e30f;
        for (int j = 0; j < KK; j++) mx = fmaxf(mx, lgs[j][h]);
        float s = 0.0f;
        for (int j = 0; j < KK; j++) {
            float ex = expf(lgs[j][h] - mx);
            lgs[j][h] = ex;
            s += ex;
        }
        float iv = 1.0f / s;
        for (int j = 0; j < KK; j++) lgs[j][h] *= iv;
    }
    __syncthreads();

    // ---- P4: attention-weighted sums ----
    if (tid < 64) {
        int e = tid, h = e >> 4;
        float acc = 0.0f;
        #pragma unroll
        for (int j = 0; j < KK; j++) acc += lgs[j][h] * v0s[j][e];
        o0s[e] = acc;
    } else if (tid < 112) {
        int idx = tid - 64, e = idx / 3, m = idx % 3, h = e >> 2;
        float acc = 0.0f;
        #pragma unroll
        for (int j = 0; j < KK; j++) acc += lgs[j][h] * v1s[j][e * 3 + m];
        o1s[idx] = acc;
    }
    __syncthreads();

    // ---- P5: output projection + residual ----
    if (tid < 64) {
        int c = tid;
        float acc = 0.0f;
        #pragma unroll
        for (int e = 0; e < D0; e++) acc += o0s[e] * Wo0[e * D0 + c];
        f0b[(size_t)node * D0 + c] += acc;
    } else if (tid < 112) {
        int idx = tid - 64, f = idx / 3, m = idx % 3;
        float acc = 0.0f;
        #pragma unroll
        for (int c = 0; c < D1; c++) acc += o1s[c * 3 + m] * Wo1[c * D1 + f];
        f1b[(size_t)node * D13 + idx] += acc;
    }
}

// ---------------- fused FFN (prenorm + MLPs + gate) ----------------
__global__ __launch_bounds__(256) void ffn_kernel(
    const float* __restrict__ F0w1, const float* __restrict__ F0w2,
    const float* __restrict__ F1w1, const float* __restrict__ F1w2,
    float* __restrict__ f0b, float* __restrict__ f1b) {

    int node = blockIdx.x;
    int tid  = threadIdx.x;
    __shared__ float g0s[D0], g1s[D13], ts[256], us[D13 * 4];  // us: 64 x 3

    if (tid < 64) {
        float x  = f0b[(size_t)node * D0 + tid];
        float mu = wred(x) * (1.0f / D0);
        float dv = x - mu;
        float var = wred(dv * dv) * (1.0f / D0);
        g0s[tid] = dv * rsqrtf(var + EPS);
    } else if (tid < 128) {
        int lane = tid - 64;
        float w = (lane < D13) ? f1b[(size_t)node * D13 + lane] : 0.0f;
        float t = wred(w * w);
        float rms = rsqrtf(t * (1.0f / D1) + EPS);
        if (lane < D13) g1s[lane] = w * rms;
    }
    __syncthreads();

    {   // hidden layer of scalar FFN (d0 -> 4*d0 = 256)
        float acc = 0.0f;
        #pragma unroll
        for (int c = 0; c < D0; c++) acc += g0s[c] * F0w1[c * 256 + tid];
        ts[tid] = gelu_t(acc);
    }
    if (tid < 192) {  // u1 = g1 @ F1w1 : (d1,3) -> (64,3)
        int e = tid / 3, m = tid % 3;
        float acc = 0.0f;
        #pragma unroll
        for (int c = 0; c < D1; c++) acc += g1s[c * 3 + m] * F1w1[c * 64 + e];
        us[tid] = acc;
    }
    __syncthreads();

    if (tid < 64) {  // gate
        int e = tid;
        float a = us[e * 3], b = us[e * 3 + 1], c = us[e * 3 + 2];
        float nrm = sqrtf(a * a + b * b + c * c);
        float gate = 1.0f / (1.0f + expf(-nrm));
        us[e * 3 + 0] *= gate;
        us[e * 3 + 1] *= gate;
        us[e * 3 + 2] *= gate;
    }
    __syncthreads();

    if (tid < 64) {
        int c = tid;
        float acc = 0.0f;
        #pragma unroll
        for (int j = 0; j < 256; j++) acc += ts[j] * F0w2[j * D0 + c];
        f0b[(size_t)node * D0 + c] += acc;
    } else if (tid < 112) {
        int idx = tid - 64, f = idx / 3, m = idx % 3;
        float acc = 0.0f;
        #pragma unroll
        for (int e = 0; e < 64; e++) acc += us[e * 3 + m] * F1w2[e * D1 + f];
        f1b[(size_t)node * D13 + idx] += acc;
    }
}

// ---------------- final concat ----------------
__global__ void concat_kernel(const float* __restrict__ f0b,
                              const float* __restrict__ f1b,
                              float* __restrict__ out) {
    int i = blockIdx.x * blockDim.x + threadIdx.x;
    if (i >= BB * NN * (D0 + D13)) return;
    int node = i / (D0 + D13), c = i % (D0 + D13);
    out[i] = (c < D0) ? f0b[(size_t)node * D0 + c]
                      : f1b[(size_t)node * D13 + (c - D0)];
}

extern "C" void kernel_launch(void* const* d_in, const int* in_sizes, int n_in,
                              void* d_out, int out_size, void* d_ws, size_t ws_size,
                              hipStream_t stream) {
    const float* f0     = (const float*)d_in[0];
    const float* f1     = (const float*)d_in[1];
    const float* coords = (const float*)d_in[2];
    const int*   nbr    = (const int*)d_in[3];
    const float* Wq0    = (const float*)d_in[4];
    const float* Wq1    = (const float*)d_in[5];
    const float* Wk00   = (const float*)d_in[6];
    const float* Wk10   = (const float*)d_in[7];
    const float* Wk01   = (const float*)d_in[8];
    const float* Wk11   = (const float*)d_in[9];
    const float* Wk11r  = (const float*)d_in[10];
    const float* Wv00   = (const float*)d_in[11];
    const float* Wv10   = (const float*)d_in[12];
    const float* Wv01   = (const float*)d_in[13];
    const float* Wv11   = (const float*)d_in[14];
    const float* Wv11r  = (const float*)d_in[15];
    const float* Rw1    = (const float*)d_in[16];
    const float* Rb1    = (const float*)d_in[17];
    const float* Rw20   = (const float*)d_in[18];
    const float* Rw21   = (const float*)d_in[19];
    const float* Wo0    = (const float*)d_in[20];
    const float* Wo1    = (const float*)d_in[21];
    const float* F0w1   = (const float*)d_in[22];
    const float* F0w2   = (const float*)d_in[23];
    const float* F1w1   = (const float*)d_in[24];
    const float* F1w2   = (const float*)d_in[25];
    float* out = (float*)d_out;

    // workspace layout
    float* ws    = (float*)d_ws;
    float* f0b   = ws;                 ws += (size_t)BB * NN * D0;    // 524288
    float* f1b   = ws;                 ws += (size_t)BB * NN * D13;   // 393216
    float* g0b   = ws;                 ws += (size_t)BB * NN * D0;
    float* g1b   = ws;                 ws += (size_t)BB * NN * D13;
    float* rhatb = ws;                 ws += (size_t)BB * NN * KK * 3;
    float* distb = ws;                 ws += (size_t)BB * NN * KK;

    int nodes = BB * NN;
    int edges = BB * NN * KK;

    geom_kernel<<<(edges + 255) / 256, 256, 0, stream>>>(coords, nbr, rhatb, distb);
    hipMemcpyAsync(f0b, f0, (size_t)nodes * D0 * sizeof(float),
                   hipMemcpyDeviceToDevice, stream);
    hipMemcpyAsync(f1b, f1, (size_t)nodes * D13 * sizeof(float),
                   hipMemcpyDeviceToDevice, stream);

    for (int l = 0; l < NLAYER; l++) {
        prenorm_kernel<<<nodes, 64, 0, stream>>>(f0b, f1b, g0b, g1b);
        attn_kernel<<<nodes, 256, 0, stream>>>(
            g0b, g1b, nbr, rhatb, distb,
            Wq0 + l * D0 * D0, Wq1 + l * D1 * D1,
            Wk00 + l * D0 * D0, Wk10 + l * D1 * D0,
            Wk01 + l * D0 * D1, Wk11 + l * D1 * D1, Wk11r + l * D1 * D1,
            Wv00 + l * D0 * D0, Wv10 + l * D1 * D0,
            Wv01 + l * D0 * D1, Wv11 + l * D1 * D1, Wv11r + l * D1 * D1,
            Rw1 + l * RHD, Rb1 + l * RHD,
            Rw20 + l * RHD * D0, Rw21 + l * RHD * D1,
            Wo0 + l * D0 * D0, Wo1 + l * D1 * D1,
            f0b, f1b);
        ffn_kernel<<<nodes, 256, 0, stream>>>(
            F0w1 + l * D0 * 256, F0w2 + l * 256 * D0,
            F1w1 + l * D1 * 64, F1w2 + l * 64 * D1,
            f0b, f1b);
    }

    concat_kernel<<<(nodes * (D0 + D13) + 255) / 256, 256, 0, stream>>>(f0b, f1b, out);
}